// Round 19
// baseline (306.310 us; speedup 1.0000x reference)
//
#include <hip/hip_runtime.h>
#include <hip/hip_bf16.h>
#include <cstdint>
#include <cstddef>

namespace {

constexpr int NCLS   = 32;
constexpr int KSHOT  = 5;
constexpr int FDIM   = 21168;   // 3*84*84
constexpr int KPAD   = 21248;   // 332 * 64
constexpr int DDIM   = 1600;
constexpr int NROW   = 512;     // 32 proto + 480 query
constexpr int NQROW  = 480;
constexpr int NKT    = 332;     // K tiles of 64
constexpr int MAXS   = 18;      // grid = 14*18 = 252 <= 256 (1 block/CU)

using short8 = __attribute__((ext_vector_type(8))) short;
using f32x4  = __attribute__((ext_vector_type(4))) float;

__device__ __forceinline__ unsigned short f2bf(float x) {
    union { float f; unsigned u; } v; v.f = x;
    unsigned r = v.u + 0x7fffu + ((v.u >> 16) & 1u);   // RNE
    return (unsigned short)(r >> 16);
}

// cast-based convert: pairs fuse to v_cvt_pk_bf16_f32
__device__ __forceinline__ unsigned short f2bfc(float x) {
    __hip_bfloat16 h = __float2bfloat16(x);
    unsigned short u;
    __builtin_memcpy(&u, &h, 2);
    return u;
}

__device__ __forceinline__ float bf2f(unsigned short u) {
    union { unsigned u; float f; } v; v.u = (unsigned)u << 16;
    return v.f;
}

// ---------------------------------------------------------------------------
// Kernel 1: build A_bf16 [512][KPAD]; rows 0..31 = 5-shot mean, rest = query.
// ---------------------------------------------------------------------------
__global__ void prep_A(const float* __restrict__ supp,
                       const float* __restrict__ query,
                       unsigned short* __restrict__ A) {
    const int r = blockIdx.y;
    const int u = blockIdx.x * blockDim.x + threadIdx.x;
    if (u >= KPAD / 4) return;
    const int c = u * 4;
    float4 v = make_float4(0.f, 0.f, 0.f, 0.f);
    if (c < FDIM) {   // FDIM % 4 == 0
        if (r < NCLS) {
            const float* s = supp + (size_t)r * KSHOT * FDIM + c;
            float4 a0 = *(const float4*)(s);
            float4 a1 = *(const float4*)(s + FDIM);
            float4 a2 = *(const float4*)(s + 2 * FDIM);
            float4 a3 = *(const float4*)(s + 3 * FDIM);
            float4 a4 = *(const float4*)(s + 4 * FDIM);
            v.x = (a0.x + a1.x + a2.x + a3.x + a4.x) * 0.2f;
            v.y = (a0.y + a1.y + a2.y + a3.y + a4.y) * 0.2f;
            v.z = (a0.z + a1.z + a2.z + a3.z + a4.z) * 0.2f;
            v.w = (a0.w + a1.w + a2.w + a3.w + a4.w) * 0.2f;
        } else {
            v = *(const float4*)(query + (size_t)(r - NCLS) * FDIM + c);
        }
    }
    ushort4 o;
    o.x = f2bf(v.x); o.y = f2bf(v.y); o.z = f2bf(v.z); o.w = f2bf(v.w);
    *(ushort4*)(A + (size_t)r * KPAD + c) = o;
}

// ---------------------------------------------------------------------------
// Kernel 2: fused GEMM, 2-phase with FULL-TILE VMEM windows.
// BM=BN=256, BK=64, 1024 threads = 16 waves (4m x 4n), wave tile 64x64,
// acc[4][4]. Key fix vs R16: wv registers are double-buffered (wvA/wvB,
// 2-unrolled loop, no moves) so PACK runs AFTER COMPUTE, consuming W loaded
// one full tile earlier; every VMEM op drained by the tile-end barrier was
// issued at the TOP of the tile (window = whole tile >> L3 latency).
// W staging: 2 cols x 8 k per thread (float2, 512B bursts, 8 instrs).
// LDS granule map g ^ ((col>>1)&7): write = 8 granules/8 lanes = all 32
// banks (minimum rounds); read = 2 lanes/bank (free). A path = R16 verbatim.
// ---------------------------------------------------------------------------
__global__ __launch_bounds__(1024, 4) void gemm18(
        const unsigned short* __restrict__ A,    // [512][KPAD] bf16 bits
        const float* __restrict__ W,             // [FDIM][DDIM] fp32
        unsigned short* __restrict__ Cpart, int S) {  // [S][512][DDIM] bf16
    __shared__ unsigned short Abuf[2][256 * 64];   // 2 x 32 KB
    __shared__ unsigned short Bbuf[2][256 * 64];   // 2 x 32 KB

    // bijective XCD-chunk swizzle (m204); mt twins adjacent (W L2-shared)
    const int nwg = gridDim.x, orig = blockIdx.x;
    const int xcd = orig & 7, q8 = nwg >> 3, r8 = nwg & 7;
    const int wgid = (xcd < r8 ? xcd * (q8 + 1) : r8 * (q8 + 1) + (xcd - r8) * q8)
                   + (orig >> 3);

    const int s   = wgid / 14;
    const int rem = wgid % 14;
    const int mt  = rem & 1;
    const int nt  = rem >> 1;        // 0..6 (nt=6 tail)
    const int m0  = mt * 256;
    const int n0  = nt * 256;
    const int t0  = (NKT * s) / S;
    const int t1  = (NKT * (s + 1)) / S;
    const int tmax = t1 - 1;

    const int tid  = threadIdx.x;
    const int lane = tid & 63;
    const int w    = tid >> 6;       // 0..15
    const int wr   = w & 3;          // m-wave 0..3 (rows wr*64..+63)
    const int wc   = w >> 2;         // n-wave 0..3 (cols wc*64..+63)
    const int gl   = lane >> 4;      // 0..3
    const int r15  = lane & 15;

    // ---- A staging roles (glds, preswizzled source; 2 instr/thread) ----
    const int srow = lane >> 3, sblk = lane & 7;
    const unsigned short* Asrc[2];
    int AdstOff[2];
    #pragma unroll
    for (int i = 0; i < 2; ++i) {
        const int r = w * 16 + i * 8 + srow;     // local row 0..255
        Asrc[i] = A + (size_t)(m0 + r) * KPAD + (size_t)((sblk ^ (r & 7)) * 8);
        AdstOff[i] = (w * 16 + i * 8) * 64;
    }

    // ---- B staging roles: 2 cols x 8 k per thread (float2 bursts) ----
    const int c2   = (tid & 127) * 2;     // local col pair base 0..254
    const int kseg = tid >> 7;            // 0..7, k = kseg*8..+7
    const int ncb  = min(n0 + c2, DDIM - 2);   // float2-safe clamp
    const float* Wp = W + ncb;
    // granule = kseg ^ ((c2>>1)&7); both cols share it (c2 even)
    const int wg0 = (c2 + 0) * 64 + ((kseg ^ ((c2 >> 1) & 7)) * 8);
    const int wg1 = wg0 + 64;

    f32x4 acc[4][4];
    #pragma unroll
    for (int i = 0; i < 4; ++i)
        #pragma unroll
        for (int j = 0; j < 4; ++j)
            acc[i][j] = (f32x4){0.f, 0.f, 0.f, 0.f};

    float2 wvA[8], wvB[8];

#define LOAD_W(wv, t) { const int kb_ = (t) * 64 + kseg * 8; _Pragma("unroll") \
    for (int i = 0; i < 8; ++i) { \
        const int k_ = kb_ + i; \
        wv[i] = (k_ < FDIM) ? *(const float2*)(Wp + (size_t)k_ * DDIM) \
                            : make_float2(0.f, 0.f); } }

#define PACK_B(buf, wv) { uint4 P0, P1; \
    P0.x = f2bfc(wv[0].x) | ((unsigned)f2bfc(wv[1].x) << 16); \
    P0.y = f2bfc(wv[2].x) | ((unsigned)f2bfc(wv[3].x) << 16); \
    P0.z = f2bfc(wv[4].x) | ((unsigned)f2bfc(wv[5].x) << 16); \
    P0.w = f2bfc(wv[6].x) | ((unsigned)f2bfc(wv[7].x) << 16); \
    P1.x = f2bfc(wv[0].y) | ((unsigned)f2bfc(wv[1].y) << 16); \
    P1.y = f2bfc(wv[2].y) | ((unsigned)f2bfc(wv[3].y) << 16); \
    P1.z = f2bfc(wv[4].y) | ((unsigned)f2bfc(wv[5].y) << 16); \
    P1.w = f2bfc(wv[6].y) | ((unsigned)f2bfc(wv[7].y) << 16); \
    *(uint4*)&Bbuf[buf][wg0] = P0; \
    *(uint4*)&Bbuf[buf][wg1] = P1; }

#define GLDS_A(buf, t) { _Pragma("unroll") \
    for (int i = 0; i < 2; ++i) \
        __builtin_amdgcn_global_load_lds( \
            (const __attribute__((address_space(1))) void*)(Asrc[i] + (size_t)(t) * 64), \
            (__attribute__((address_space(3))) void*)(&Abuf[buf][AdstOff[i]]), 16, 0, 0); }

#define COMPUTE(buf) { _Pragma("unroll") \
    for (int kk = 0; kk < 2; ++kk) { \
        const int q_ = kk * 4 + gl; \
        short8 bf_[4]; \
        _Pragma("unroll") \
        for (int ns = 0; ns < 4; ++ns) { \
            const int n_ = wc * 64 + ns * 16 + r15; \
            bf_[ns] = *(const short8*)&Bbuf[buf][n_ * 64 + ((q_ ^ ((n_ >> 1) & 7)) * 8)]; \
        } \
        _Pragma("unroll") \
        for (int ms = 0; ms < 4; ++ms) { \
            const int R_ = wr * 64 + ms * 16 + r15; \
            short8 af_ = *(const short8*)&Abuf[buf][R_ * 64 + ((q_ ^ (R_ & 7)) * 8)]; \
            _Pragma("unroll") \
            for (int ns = 0; ns < 4; ++ns) \
                acc[ms][ns] = __builtin_amdgcn_mfma_f32_16x16x32_bf16( \
                    af_, bf_[ns], acc[ms][ns], 0, 0, 0); } } }

    // ---- prologue: B(t0)->B[0]; A(t0)->A[0]; wvA = W(t0+1) ----
    LOAD_W(wvA, t0);
    PACK_B(0, wvA);                    // register deps retire W(t0)
    GLDS_A(0, t0);
    LOAD_W(wvA, min(t0 + 1, tmax));    // wvA now holds W(t0+1)
    __syncthreads();

    // ---- main loop (2-unrolled, named wv sets): invariant at tile t:
    //      A[cur]=A(t), B[cur]=B(t), wvPrev=W(t+1) (arrived last tile) ----
    int cur = 0;
    int t = t0;
    for (; t + 1 < t1; t += 2) {
        // tile t: consume wvA, prefetch into wvB
        GLDS_A(cur ^ 1, t + 1);
        LOAD_W(wvB, min(t + 2, tmax));
        COMPUTE(cur);
        PACK_B(cur ^ 1, wvA);          // W(t+1): loaded a full tile ago
        __syncthreads();
        cur ^= 1;
        // tile t+1: consume wvB, prefetch into wvA
        GLDS_A(cur ^ 1, min(t + 2, tmax));
        LOAD_W(wvA, min(t + 3, tmax));
        COMPUTE(cur);
        PACK_B(cur ^ 1, wvB);          // W(t+2)
        __syncthreads();
        cur ^= 1;
    }
    if (t < t1) {                      // odd tail: buffers already staged
        COMPUTE(cur);
    }

#undef LOAD_W
#undef PACK_B
#undef GLDS_A
#undef COMPUTE

    // ---- epilogue: bf16 split partial (guard tail cols) ----
    unsigned short* Cp = Cpart + (size_t)s * NROW * DDIM;
    #pragma unroll
    for (int ms = 0; ms < 4; ++ms) {
        const int row = m0 + wr * 64 + ms * 16 + gl * 4;
        #pragma unroll
        for (int ns = 0; ns < 4; ++ns) {
            const int col = n0 + wc * 64 + ns * 16 + r15;
            if (col < DDIM) {
                #pragma unroll
                for (int r = 0; r < 4; ++r)
                    Cp[(size_t)(row + r) * DDIM + col] = f2bfc(acc[ms][ns][r]);
            }
        }
    }
}

// ---------------------------------------------------------------------------
// Kernel 3: sum S bf16 split partials -> C (f32) + per-row inverse norm.
// ---------------------------------------------------------------------------
__global__ void reduce_norm(const unsigned short* __restrict__ Cpart,
                            float* __restrict__ C,
                            float* __restrict__ inv_norm, int S) {
    const int row = blockIdx.x;
    const int tid = threadIdx.x;
    float acc = 0.f;
    for (int c4 = tid * 4; c4 < DDIM; c4 += 1024) {
        float4 v = make_float4(0.f, 0.f, 0.f, 0.f);
        for (int s2 = 0; s2 < S; ++s2) {
            ushort4 u = *(const ushort4*)&Cpart[((size_t)s2 * NROW + row) * DDIM + c4];
            v.x += bf2f(u.x); v.y += bf2f(u.y);
            v.z += bf2f(u.z); v.w += bf2f(u.w);
        }
        *(float4*)&C[(size_t)row * DDIM + c4] = v;
        acc += v.x * v.x + v.y * v.y + v.z * v.z + v.w * v.w;
    }
    __shared__ float red[4];
    #pragma unroll
    for (int off = 32; off > 0; off >>= 1) acc += __shfl_xor(acc, off);
    if ((tid & 63) == 0) red[tid >> 6] = acc;
    __syncthreads();
    if (tid == 0) {
        float a = red[0] + red[1] + red[2] + red[3];
        inv_norm[row] = 1.f / fmaxf(sqrtf(a), 1e-8f);
    }
}

// ---------------------------------------------------------------------------
// Kernel 4: fused cosine-sim (480x32) + log_softmax. One block per query row.
// ---------------------------------------------------------------------------
__global__ void simlog(const float* __restrict__ C,
                       const float* __restrict__ inv_norm,
                       float* __restrict__ out) {
    __shared__ float qs[DDIM];
    __shared__ float sims[NCLS];
    const int r = blockIdx.x;
    const int tid = threadIdx.x;
    const float* qrow = C + (size_t)(NCLS + r) * DDIM;
    for (int c = tid; c < DDIM; c += 256) qs[c] = qrow[c];
    __syncthreads();
    const float invq = inv_norm[NCLS + r];
    const int lane = tid & 63, w = tid >> 6;
    #pragma unroll
    for (int j = 0; j < 8; ++j) {
        const int p = w * 8 + j;
        const float* prow = C + (size_t)p * DDIM;
        float d = 0.f;
        for (int c = lane; c < DDIM; c += 64) d += qs[c] * prow[c];
        #pragma unroll
        for (int off = 32; off > 0; off >>= 1) d += __shfl_xor(d, off);
        if (lane == 0) sims[p] = d * invq * inv_norm[p];
    }
    __syncthreads();
    if (w == 0) {
        float v = (lane < NCLS) ? sims[lane] : -1e30f;
        float m = v;
        #pragma unroll
        for (int off = 32; off > 0; off >>= 1) m = fmaxf(m, __shfl_xor(m, off));
        float e = (lane < NCLS) ? expf(v - m) : 0.f;
        float ss = e;
        #pragma unroll
        for (int off = 32; off > 0; off >>= 1) ss += __shfl_xor(ss, off);
        if (lane < NCLS) out[(size_t)r * NCLS + lane] = v - m - logf(ss);
    }
}

} // anonymous namespace

// ws layout (bytes):
//   A_bf16   : 512*21248*2  = 21,757,952
//   Cpart bf : S*512*1600*2 = S*1,638,400   (S=18 -> 29,491,200)
//   C (f32)  : 3,276,800
//   invn     : 4,096
// S=18 total ~54.5 MB; S auto-shrinks if ws_size is smaller.

extern "C" void kernel_launch(void* const* d_in, const int* in_sizes, int n_in,
                              void* d_out, int out_size, void* d_ws, size_t ws_size,
                              hipStream_t stream) {
    const float* supp  = (const float*)d_in[0];
    const float* query = (const float*)d_in[1];
    const float* Wenc  = (const float*)d_in[2];
    float* out = (float*)d_out;

    const size_t fixedA = 21757952;
    const size_t slotBf = (size_t)NROW * DDIM * 2;
    const size_t slotC  = (size_t)NROW * DDIM * 4;

    int S = MAXS;
    if (ws_size > fixedA + slotC + 4096) {
        size_t avail = (ws_size - fixedA - slotC - 4096) / slotBf;
        if ((size_t)S > avail) S = (int)avail;
    }
    if (S < 1) S = 1;

    char* ws = (char*)d_ws;
    unsigned short* A = (unsigned short*)ws;
    unsigned short* Cpart = (unsigned short*)(ws + fixedA);
    float* C        = (float*)(ws + fixedA + (size_t)S * slotBf);
    float* inv_norm = (float*)(ws + fixedA + (size_t)S * slotBf + slotC);

    hipLaunchKernelGGL(prep_A, dim3((KPAD / 4 + 255) / 256, NROW), dim3(256),
                       0, stream, supp, query, A);
    hipLaunchKernelGGL(gemm18, dim3(14 * S), dim3(1024), 0, stream,
                       A, Wenc, Cpart, S);
    hipLaunchKernelGGL(reduce_norm, dim3(NROW), dim3(256), 0, stream,
                       Cpart, C, inv_norm, S);
    hipLaunchKernelGGL(simlog, dim3(NQROW), dim3(256), 0, stream,
                       C, inv_norm, out);
}

// Round 20
// 139.454 us; speedup vs baseline: 2.1965x; 2.1965x over previous
//
#include <hip/hip_runtime.h>
#include <hip/hip_bf16.h>
#include <cstdint>
#include <cstddef>

namespace {

constexpr int NCLS   = 32;
constexpr int KSHOT  = 5;
constexpr int FDIM   = 21168;   // 3*84*84
constexpr int KPAD   = 21248;   // 332 * 64
constexpr int DDIM   = 1600;
constexpr int NROW   = 512;     // 32 proto + 480 query
constexpr int NQROW  = 480;
constexpr int NKT    = 332;     // K tiles of 64
constexpr int MAXS   = 18;      // grid = 14*18 = 252 <= 256 (1 block/CU)

using short8 = __attribute__((ext_vector_type(8))) short;
using f32x4  = __attribute__((ext_vector_type(4))) float;

__device__ __forceinline__ unsigned short f2bf(float x) {
    union { float f; unsigned u; } v; v.f = x;
    unsigned r = v.u + 0x7fffu + ((v.u >> 16) & 1u);   // RNE
    return (unsigned short)(r >> 16);
}

// cast-based convert: pairs fuse to v_cvt_pk_bf16_f32
__device__ __forceinline__ unsigned short f2bfc(float x) {
    __hip_bfloat16 h = __float2bfloat16(x);
    unsigned short u;
    __builtin_memcpy(&u, &h, 2);
    return u;
}

__device__ __forceinline__ float bf2f(unsigned short u) {
    union { unsigned u; float f; } v; v.u = (unsigned)u << 16;
    return v.f;
}

// ---------------------------------------------------------------------------
// Kernel 1: build A_bf16 [512][KPAD]; rows 0..31 = 5-shot mean, rest = query.
// ---------------------------------------------------------------------------
__global__ void prep_A(const float* __restrict__ supp,
                       const float* __restrict__ query,
                       unsigned short* __restrict__ A) {
    const int r = blockIdx.y;
    const int u = blockIdx.x * blockDim.x + threadIdx.x;
    if (u >= KPAD / 4) return;
    const int c = u * 4;
    float4 v = make_float4(0.f, 0.f, 0.f, 0.f);
    if (c < FDIM) {   // FDIM % 4 == 0
        if (r < NCLS) {
            const float* s = supp + (size_t)r * KSHOT * FDIM + c;
            float4 a0 = *(const float4*)(s);
            float4 a1 = *(const float4*)(s + FDIM);
            float4 a2 = *(const float4*)(s + 2 * FDIM);
            float4 a3 = *(const float4*)(s + 3 * FDIM);
            float4 a4 = *(const float4*)(s + 4 * FDIM);
            v.x = (a0.x + a1.x + a2.x + a3.x + a4.x) * 0.2f;
            v.y = (a0.y + a1.y + a2.y + a3.y + a4.y) * 0.2f;
            v.z = (a0.z + a1.z + a2.z + a3.z + a4.z) * 0.2f;
            v.w = (a0.w + a1.w + a2.w + a3.w + a4.w) * 0.2f;
        } else {
            v = *(const float4*)(query + (size_t)(r - NCLS) * FDIM + c);
        }
    }
    ushort4 o;
    o.x = f2bf(v.x); o.y = f2bf(v.y); o.z = f2bf(v.z); o.w = f2bf(v.w);
    *(ushort4*)(A + (size_t)r * KPAD + c) = o;
}

// ---------------------------------------------------------------------------
// Kernel 2: fused GEMM — R16 schedule + R19 LDS maps + float2 W bursts.
// BM=BN=256, BK=64, 1024 threads = 16 waves (4m x 4n), wave tile 64x64,
// acc[4][4]. A[2]: glds 16B preswizzled (measured 0-conflict).
// B[2]: 2 cols x 8 k per thread (8x float2 512B-burst loads), ONE wv set
// (16 VGPR, no spill), 2x 16B writes at granule kseg^((c2>>1)&7)
// (8 granules/wave = all 32 banks, conflict-free); read q^((n>>1)&7)
// (8 positions x 2 lanes = free). Schedule: {PACK_B(next); LOAD_W(t+2);
// GLDS_A(next); COMPUTE(cur); one __syncthreads}. Cpart in bf16.
// ---------------------------------------------------------------------------
__global__ __launch_bounds__(1024, 4) void gemm19(
        const unsigned short* __restrict__ A,    // [512][KPAD] bf16 bits
        const float* __restrict__ W,             // [FDIM][DDIM] fp32
        unsigned short* __restrict__ Cpart, int S) {  // [S][512][DDIM] bf16
    __shared__ unsigned short Abuf[2][256 * 64];   // 2 x 32 KB
    __shared__ unsigned short Bbuf[2][256 * 64];   // 2 x 32 KB

    // bijective XCD-chunk swizzle (m204); mt twins adjacent (W L2-shared)
    const int nwg = gridDim.x, orig = blockIdx.x;
    const int xcd = orig & 7, q8 = nwg >> 3, r8 = nwg & 7;
    const int wgid = (xcd < r8 ? xcd * (q8 + 1) : r8 * (q8 + 1) + (xcd - r8) * q8)
                   + (orig >> 3);

    const int s   = wgid / 14;
    const int rem = wgid % 14;
    const int mt  = rem & 1;
    const int nt  = rem >> 1;        // 0..6 (nt=6 tail)
    const int m0  = mt * 256;
    const int n0  = nt * 256;
    const int t0  = (NKT * s) / S;
    const int t1  = (NKT * (s + 1)) / S;
    const int tmax = t1 - 1;

    const int tid  = threadIdx.x;
    const int lane = tid & 63;
    const int w    = tid >> 6;       // 0..15
    const int wr   = w & 3;          // m-wave 0..3 (rows wr*64..+63)
    const int wc   = w >> 2;         // n-wave 0..3 (cols wc*64..+63)
    const int gl   = lane >> 4;      // 0..3
    const int r15  = lane & 15;

    // ---- A staging roles (glds, preswizzled source; 2 instr/thread) ----
    const int srow = lane >> 3, sblk = lane & 7;
    const unsigned short* Asrc[2];
    int AdstOff[2];
    #pragma unroll
    for (int i = 0; i < 2; ++i) {
        const int r = w * 16 + i * 8 + srow;     // local row 0..255
        Asrc[i] = A + (size_t)(m0 + r) * KPAD + (size_t)((sblk ^ (r & 7)) * 8);
        AdstOff[i] = (w * 16 + i * 8) * 64;
    }

    // ---- B staging roles: 2 cols x 8 k per thread (float2 bursts) ----
    const int c2   = (tid & 127) * 2;     // local col pair base 0..254
    const int kseg = tid >> 7;            // 0..7, k = kseg*8..+7
    const int ncb  = min(n0 + c2, DDIM - 2);   // float2-safe clamp
    const float* Wp = W + ncb;
    // 16B granule = kseg ^ ((c2>>1)&7); both cols of the pair share it
    const int wg0 = (c2 + 0) * 64 + ((kseg ^ ((c2 >> 1) & 7)) * 8);
    const int wg1 = wg0 + 64;

    f32x4 acc[4][4];
    #pragma unroll
    for (int i = 0; i < 4; ++i)
        #pragma unroll
        for (int j = 0; j < 4; ++j)
            acc[i][j] = (f32x4){0.f, 0.f, 0.f, 0.f};

    float2 wv[8];   // single set: 16 VGPR, no spill

#define LOAD_W(t) { const int kb_ = (t) * 64 + kseg * 8; _Pragma("unroll") \
    for (int i = 0; i < 8; ++i) { \
        const int k_ = kb_ + i; \
        wv[i] = (k_ < FDIM) ? *(const float2*)(Wp + (size_t)k_ * DDIM) \
                            : make_float2(0.f, 0.f); } }

#define PACK_B(buf) { uint4 P0, P1; \
    P0.x = f2bfc(wv[0].x) | ((unsigned)f2bfc(wv[1].x) << 16); \
    P0.y = f2bfc(wv[2].x) | ((unsigned)f2bfc(wv[3].x) << 16); \
    P0.z = f2bfc(wv[4].x) | ((unsigned)f2bfc(wv[5].x) << 16); \
    P0.w = f2bfc(wv[6].x) | ((unsigned)f2bfc(wv[7].x) << 16); \
    P1.x = f2bfc(wv[0].y) | ((unsigned)f2bfc(wv[1].y) << 16); \
    P1.y = f2bfc(wv[2].y) | ((unsigned)f2bfc(wv[3].y) << 16); \
    P1.z = f2bfc(wv[4].y) | ((unsigned)f2bfc(wv[5].y) << 16); \
    P1.w = f2bfc(wv[6].y) | ((unsigned)f2bfc(wv[7].y) << 16); \
    *(uint4*)&Bbuf[buf][wg0] = P0; \
    *(uint4*)&Bbuf[buf][wg1] = P1; }

#define GLDS_A(buf, t) { _Pragma("unroll") \
    for (int i = 0; i < 2; ++i) \
        __builtin_amdgcn_global_load_lds( \
            (const __attribute__((address_space(1))) void*)(Asrc[i] + (size_t)(t) * 64), \
            (__attribute__((address_space(3))) void*)(&Abuf[buf][AdstOff[i]]), 16, 0, 0); }

#define COMPUTE(buf) { _Pragma("unroll") \
    for (int kk = 0; kk < 2; ++kk) { \
        const int q_ = kk * 4 + gl; \
        short8 bf_[4]; \
        _Pragma("unroll") \
        for (int ns = 0; ns < 4; ++ns) { \
            const int n_ = wc * 64 + ns * 16 + r15; \
            bf_[ns] = *(const short8*)&Bbuf[buf][n_ * 64 + ((q_ ^ ((n_ >> 1) & 7)) * 8)]; \
        } \
        _Pragma("unroll") \
        for (int ms = 0; ms < 4; ++ms) { \
            const int R_ = wr * 64 + ms * 16 + r15; \
            short8 af_ = *(const short8*)&Abuf[buf][R_ * 64 + ((q_ ^ (R_ & 7)) * 8)]; \
            _Pragma("unroll") \
            for (int ns = 0; ns < 4; ++ns) \
                acc[ms][ns] = __builtin_amdgcn_mfma_f32_16x16x32_bf16( \
                    af_, bf_[ns], acc[ms][ns], 0, 0, 0); } } }

    // ---- prologue: B(t0)->B[0]; wv = W(t0+1); A(t0)->A[0] ----
    LOAD_W(t0);
    PACK_B(0);                         // register deps retire W(t0)
    LOAD_W(min(t0 + 1, tmax));
    GLDS_A(0, t0);
    __syncthreads();

    // ---- main loop: stage(t+1) before compute(t), 1 barrier/tile ----
    int cur = 0;
    for (int t = t0; t < t1; ++t) {
        const bool m1 = (t + 1 < t1);
        if (m1) {
            PACK_B(cur ^ 1);                 // consumes wv = W(t+1)
            LOAD_W(min(t + 2, tmax));        // wv = W(t+2)
            GLDS_A(cur ^ 1, t + 1);          // A(t+1)
        }
        COMPUTE(cur);
        __syncthreads();
        if (m1) cur ^= 1;
    }

#undef LOAD_W
#undef PACK_B
#undef GLDS_A
#undef COMPUTE

    // ---- epilogue: bf16 split partial (guard tail cols) ----
    unsigned short* Cp = Cpart + (size_t)s * NROW * DDIM;
    #pragma unroll
    for (int ms = 0; ms < 4; ++ms) {
        const int row = m0 + wr * 64 + ms * 16 + gl * 4;
        #pragma unroll
        for (int ns = 0; ns < 4; ++ns) {
            const int col = n0 + wc * 64 + ns * 16 + r15;
            if (col < DDIM) {
                #pragma unroll
                for (int r = 0; r < 4; ++r)
                    Cp[(size_t)(row + r) * DDIM + col] = f2bfc(acc[ms][ns][r]);
            }
        }
    }
}

// ---------------------------------------------------------------------------
// Kernel 3: sum S bf16 split partials -> C (f32) + per-row inverse norm.
// ---------------------------------------------------------------------------
__global__ void reduce_norm(const unsigned short* __restrict__ Cpart,
                            float* __restrict__ C,
                            float* __restrict__ inv_norm, int S) {
    const int row = blockIdx.x;
    const int tid = threadIdx.x;
    float acc = 0.f;
    for (int c4 = tid * 4; c4 < DDIM; c4 += 1024) {
        float4 v = make_float4(0.f, 0.f, 0.f, 0.f);
        for (int s2 = 0; s2 < S; ++s2) {
            ushort4 u = *(const ushort4*)&Cpart[((size_t)s2 * NROW + row) * DDIM + c4];
            v.x += bf2f(u.x); v.y += bf2f(u.y);
            v.z += bf2f(u.z); v.w += bf2f(u.w);
        }
        *(float4*)&C[(size_t)row * DDIM + c4] = v;
        acc += v.x * v.x + v.y * v.y + v.z * v.z + v.w * v.w;
    }
    __shared__ float red[4];
    #pragma unroll
    for (int off = 32; off > 0; off >>= 1) acc += __shfl_xor(acc, off);
    if ((tid & 63) == 0) red[tid >> 6] = acc;
    __syncthreads();
    if (tid == 0) {
        float a = red[0] + red[1] + red[2] + red[3];
        inv_norm[row] = 1.f / fmaxf(sqrtf(a), 1e-8f);
    }
}

// ---------------------------------------------------------------------------
// Kernel 4: fused cosine-sim (480x32) + log_softmax. One block per query row.
// ---------------------------------------------------------------------------
__global__ void simlog(const float* __restrict__ C,
                       const float* __restrict__ inv_norm,
                       float* __restrict__ out) {
    __shared__ float qs[DDIM];
    __shared__ float sims[NCLS];
    const int r = blockIdx.x;
    const int tid = threadIdx.x;
    const float* qrow = C + (size_t)(NCLS + r) * DDIM;
    for (int c = tid; c < DDIM; c += 256) qs[c] = qrow[c];
    __syncthreads();
    const float invq = inv_norm[NCLS + r];
    const int lane = tid & 63, w = tid >> 6;
    #pragma unroll
    for (int j = 0; j < 8; ++j) {
        const int p = w * 8 + j;
        const float* prow = C + (size_t)p * DDIM;
        float d = 0.f;
        for (int c = lane; c < DDIM; c += 64) d += qs[c] * prow[c];
        #pragma unroll
        for (int off = 32; off > 0; off >>= 1) d += __shfl_xor(d, off);
        if (lane == 0) sims[p] = d * invq * inv_norm[p];
    }
    __syncthreads();
    if (w == 0) {
        float v = (lane < NCLS) ? sims[lane] : -1e30f;
        float m = v;
        #pragma unroll
        for (int off = 32; off > 0; off >>= 1) m = fmaxf(m, __shfl_xor(m, off));
        float e = (lane < NCLS) ? expf(v - m) : 0.f;
        float ss = e;
        #pragma unroll
        for (int off = 32; off > 0; off >>= 1) ss += __shfl_xor(ss, off);
        if (lane < NCLS) out[(size_t)r * NCLS + lane] = v - m - logf(ss);
    }
}

} // anonymous namespace

// ws layout (bytes):
//   A_bf16   : 512*21248*2  = 21,757,952
//   Cpart bf : S*512*1600*2 = S*1,638,400   (S=18 -> 29,491,200)
//   C (f32)  : 3,276,800
//   invn     : 4,096
// S=18 total ~54.5 MB; S auto-shrinks if ws_size is smaller.

extern "C" void kernel_launch(void* const* d_in, const int* in_sizes, int n_in,
                              void* d_out, int out_size, void* d_ws, size_t ws_size,
                              hipStream_t stream) {
    const float* supp  = (const float*)d_in[0];
    const float* query = (const float*)d_in[1];
    const float* Wenc  = (const float*)d_in[2];
    float* out = (float*)d_out;

    const size_t fixedA = 21757952;
    const size_t slotBf = (size_t)NROW * DDIM * 2;
    const size_t slotC  = (size_t)NROW * DDIM * 4;

    int S = MAXS;
    if (ws_size > fixedA + slotC + 4096) {
        size_t avail = (ws_size - fixedA - slotC - 4096) / slotBf;
        if ((size_t)S > avail) S = (int)avail;
    }
    if (S < 1) S = 1;

    char* ws = (char*)d_ws;
    unsigned short* A = (unsigned short*)ws;
    unsigned short* Cpart = (unsigned short*)(ws + fixedA);
    float* C        = (float*)(ws + fixedA + (size_t)S * slotBf);
    float* inv_norm = (float*)(ws + fixedA + (size_t)S * slotBf + slotC);

    hipLaunchKernelGGL(prep_A, dim3((KPAD / 4 + 255) / 256, NROW), dim3(256),
                       0, stream, supp, query, A);
    hipLaunchKernelGGL(gemm19, dim3(14 * S), dim3(1024), 0, stream,
                       A, Wenc, Cpart, S);
    hipLaunchKernelGGL(reduce_norm, dim3(NROW), dim3(256), 0, stream,
                       Cpart, C, inv_norm, S);
    hipLaunchKernelGGL(simlog, dim3(NQROW), dim3(256), 0, stream,
                       C, inv_norm, out);
}